// Round 9
// baseline (115.439 us; speedup 1.0000x reference)
//
#include <hip/hip_runtime.h>

typedef float v2f __attribute__((ext_vector_type(2)));

#define NN 4096
#define TTOT 8192

constexpr int S    = 32;      // t per thread
constexpr int HALO = 4;       // dependency cone of 4 kernel-2 layers
constexpr int TN   = 64;      // n-rows per block (= lanes)
constexpr int TB   = 4 * S;   // 128 t-cols per block (4 waves)

__device__ __forceinline__ float fexp2(float x) {
#if __has_builtin(__builtin_amdgcn_exp2f)
    return __builtin_amdgcn_exp2f(x);
#else
    return exp2f(x);
#endif
}
__device__ __forceinline__ float frcp(float x) {
#if __has_builtin(__builtin_amdgcn_rcpf)
    return __builtin_amdgcn_rcpf(x);
#else
    return 1.0f / x;
#endif
}
__device__ __forceinline__ v2f splat(float x) { v2f r = {x, x}; return r; }

__global__ __launch_bounds__(256, 8) void gdcn_kernel(
    const float* __restrict__ x,
    const float* __restrict__ start_w,
    const float* __restrict__ start_b,
    const float* __restrict__ filter_w,
    const float* __restrict__ filter_b,
    const float* __restrict__ gate_w,
    const float* __restrict__ gate_b,
    float* __restrict__ out)
{
    const int tid = threadIdx.x;
    const int bn  = blockIdx.x & 63;          // 64 n-blocks (fast dim)
    const int bt  = blockIdx.x >> 6;
    const int n0  = bn * TN;
    const int t0  = bt * TB;

    const int nl = tid & 63;                  // lane -> n row
    const int ts = tid >> 6;                  // wave -> t segment (wave-uniform edge)
    const int tbase = t0 + ts * S;

    const float* xr = x + (size_t)(n0 + nl) * TTOT + tbase;

    float v[S + HALO + 1];                    // +1 garbage slot: even-pair loops
    const bool edge = (tbase + S + HALO > TTOT);   // only the grid's last segment
    if (!edge) {
        #pragma unroll
        for (int q = 0; q < (S + HALO) / 4; ++q) {
            float4 f4 = *reinterpret_cast<const float4*>(xr + 4 * q);
            v[4*q+0] = f4.x; v[4*q+1] = f4.y; v[4*q+2] = f4.z; v[4*q+3] = f4.w;
        }
    } else {
        #pragma unroll
        for (int s = 0; s < S + HALO; ++s)
            v[s] = (tbase + s < TTOT) ? xr[s] : 0.0f;
    }
    v[S + HALO] = 0.0f;                       // keep garbage slot NaN-free

    constexpr float LOG2E = 1.4426950408889634f;
    const float sw = start_w[0], sb = start_b[0];

    // layer-0 coefficients with start conv folded in:
    // z = sw*x + sb;  F = f0*z[s] + f1*z[s+1] + fb
    //   = (f0*sw)*x[s] + (f1*sw)*x[s+1] + (fb + (f0+f1)*sb)
    // (then scaled by 2*log2e / -log2e as before)

    // NOTE on edge semantics: reference zero-pads AFTER the start conv, i.e.
    // z[8192] = 0 exactly. With folding, x-slot for t>=8192 must represent
    // z=0: since z = sw*x+sb, use x_pad = -sb/sw ... avoided entirely by
    // handling the edge segment explicitly below (it zeroes halo slots after
    // layer-0, and for layer-0 we pre-substitute z=0 -> contribution f1*0:
    // we instead compute layer-0 on z directly for the edge segment).

    #pragma unroll
    for (int i = 0; i < 4; ++i) {
        float f0 = filter_w[2*i]   * (2.0f * LOG2E);
        float f1 = filter_w[2*i+1] * (2.0f * LOG2E);
        float fb = filter_b[i]     * (2.0f * LOG2E);
        float g0 = -gate_w[2*i]    * LOG2E;
        float g1 = -gate_w[2*i+1]  * LOG2E;
        float gb = -gate_b[i]      * LOG2E;
        if (i == 0) {
            // fold start conv (valid for non-pad slots; edge handled below)
            fb = fb + (f0 + f1) * sb;
            f0 = f0 * sw;  f1 = f1 * sw;
            gb = gb + (g0 + g1) * sb;
            g0 = g0 * sw;  g1 = g1 * sw;
            if (edge) {
                // convert pad slots so folded form yields z=0 contribution:
                // need sw*x_pad + sb == 0  ->  x_pad = -sb/sw
                const float xpad = -sb * frcp(sw);
                #pragma unroll
                for (int s = 0; s < S + HALO; ++s)
                    if (tbase + s >= TTOT) v[s] = xpad;
            }
        }
        const int len  = S + HALO - 1 - i;        // 35,34,33,32
        const int npair = (len + 1) / 2;          // 18,17,17,16

        #pragma unroll
        for (int p = 0; p < npair; ++p) {
            const int s = 2 * p;
            v2f a = { v[s],   v[s+1] };
            v2f b = { v[s+1], v[s+2] };
            v2f tf = a * splat(f0) + b * splat(f1) + splat(fb);
            v2f tg = a * splat(g0) + b * splat(g1) + splat(gb);
            if (i == 0) {   // layer-0 arg unbounded: keep ef/eg finite
                tf.x = fminf(tf.x, 60.0f); tf.y = fminf(tf.y, 60.0f);
                tg.x = fminf(tg.x, 60.0f); tg.y = fminf(tg.y, 60.0f);
            }
            v2f ef = { fexp2(tf.x), fexp2(tf.y) };
            v2f eg = { fexp2(tg.x), fexp2(tg.y) };
            v2f num = ef - splat(1.0f);
            v2f den = (ef + splat(1.0f)) * (eg + splat(1.0f));
            v2f r   = { frcp(den.x), frcp(den.y) };
            v2f res = num * r;
            v[s] = res.x; v[s+1] = res.y;
        }
        if (edge) {         // re-zero pad slots (per-layer zero-pad semantics)
            #pragma unroll
            for (int s = 0; s <= len; ++s)
                if (tbase + s >= TTOT) v[s] = 0.0f;
        }
    }

    // direct transposed store: out[t][n]; 64 lanes x 4B = contiguous 256B per
    // wave-store -> fully coalesced, no LDS, no barriers
    float* op = out + (size_t)tbase * NN + n0 + nl;
    #pragma unroll
    for (int s = 0; s < S; ++s)
        op[(size_t)s * NN] = v[s];
}

extern "C" void kernel_launch(void* const* d_in, const int* in_sizes, int n_in,
                              void* d_out, int out_size, void* d_ws, size_t ws_size,
                              hipStream_t stream) {
    const float* x  = (const float*)d_in[0];
    const float* sw = (const float*)d_in[1];
    const float* sb = (const float*)d_in[2];
    const float* fw = (const float*)d_in[3];
    const float* fb = (const float*)d_in[4];
    const float* gw = (const float*)d_in[5];
    const float* gb = (const float*)d_in[6];
    float* out = (float*)d_out;

    dim3 grid((NN / TN) * (TTOT / TB));   // 64 * 64 = 4096 blocks
    gdcn_kernel<<<grid, 256, 0, stream>>>(x, sw, sb, fw, fb, gw, gb, out);
}

// Round 10
// 65.261 us; speedup vs baseline: 1.7689x; 1.7689x over previous
//
#include <hip/hip_runtime.h>

typedef float v2f __attribute__((ext_vector_type(2)));

#define NN 4096
#define TTOT 8192

constexpr int S    = 32;      // t per thread
constexpr int HALO = 4;       // dependency cone of 4 kernel-2 layers
constexpr int TN   = 64;      // n-rows per block (= lanes)
constexpr int TB   = 4 * S;   // 128 t-cols per block (4 waves)

__device__ __forceinline__ float fexp2(float x) {
#if __has_builtin(__builtin_amdgcn_exp2f)
    return __builtin_amdgcn_exp2f(x);
#else
    return exp2f(x);
#endif
}
__device__ __forceinline__ float frcp(float x) {
#if __has_builtin(__builtin_amdgcn_rcpf)
    return __builtin_amdgcn_rcpf(x);
#else
    return 1.0f / x;
#endif
}
__device__ __forceinline__ v2f splat(float x) { v2f r = {x, x}; return r; }

// __launch_bounds__(256, 4): 4 waves/EU -> 128 VGPR budget. The previous
// (256, 8) forced a 32-VGPR allocation with v[36] live -> massive scratch
// spills (seen as WRITE_SIZE 131->252 MB in R9, FETCH over-read in R2-R9).
__global__ __launch_bounds__(256, 4) void gdcn_kernel(
    const float* __restrict__ x,
    const float* __restrict__ start_w,
    const float* __restrict__ start_b,
    const float* __restrict__ filter_w,
    const float* __restrict__ filter_b,
    const float* __restrict__ gate_w,
    const float* __restrict__ gate_b,
    float* __restrict__ out)
{
    const int tid = threadIdx.x;
    const int bn  = blockIdx.x & 63;          // 64 n-blocks (fast dim)
    const int bt  = blockIdx.x >> 6;
    const int n0  = bn * TN;
    const int t0  = bt * TB;

    const int nl = tid & 63;                  // lane -> n row
    const int ts = tid >> 6;                  // wave -> t segment (wave-uniform edge)
    const int tbase = t0 + ts * S;

    const float* xr = x + (size_t)(n0 + nl) * TTOT + tbase;

    float v[S + HALO];
    const bool edge = (tbase + S + HALO > TTOT);   // only the grid's last segment
    if (!edge) {
        #pragma unroll
        for (int q = 0; q < (S + HALO) / 4; ++q) {
            float4 f4 = *reinterpret_cast<const float4*>(xr + 4 * q);
            v[4*q+0] = f4.x; v[4*q+1] = f4.y; v[4*q+2] = f4.z; v[4*q+3] = f4.w;
        }
    } else {
        #pragma unroll
        for (int s = 0; s < S + HALO; ++s)
            v[s] = (tbase + s < TTOT) ? xr[s] : 0.0f;
    }

    constexpr float LOG2E = 1.4426950408889634f;

    // start 1x1 conv
    {
        const float sw = start_w[0], sb = start_b[0];
        #pragma unroll
        for (int s = 0; s < S + HALO; ++s) v[s] = fmaf(v[s], sw, sb);
        if (edge) {
            #pragma unroll
            for (int s = 0; s < S + HALO; ++s)
                if (tbase + s >= TTOT) v[s] = 0.0f;   // per-layer zero pad
        }
    }

    // 4 gated layers:
    // tanh(F)*sigmoid(G) = (ef-1) * rcp((ef+1)*(1+eg)), ef=2^(2*log2e*F), eg=2^(-log2e*G)
    #pragma unroll
    for (int i = 0; i < 4; ++i) {
        const float ff0 = filter_w[2*i]   * (2.0f * LOG2E);
        const float ff1 = filter_w[2*i+1] * (2.0f * LOG2E);
        const float ffb = filter_b[i]     * (2.0f * LOG2E);
        const float gg0 = -gate_w[2*i]    * LOG2E;
        const float gg1 = -gate_w[2*i+1]  * LOG2E;
        const float ggb = -gate_b[i]      * LOG2E;
        const int len = S + HALO - 1 - i;     // 35,34,33,32

        #pragma unroll
        for (int s = 0; s + 1 < len; s += 2) {
            v2f a = { v[s],   v[s+1] };
            v2f b = { v[s+1], v[s+2] };
            v2f tf = a * splat(ff0) + b * splat(ff1) + splat(ffb);
            v2f tg = a * splat(gg0) + b * splat(gg1) + splat(ggb);
            if (i == 0) {   // layer-0 input unbounded: keep den in normal range
                tf.x = fminf(tf.x, 60.0f); tf.y = fminf(tf.y, 60.0f);
                tg.x = fminf(tg.x, 60.0f); tg.y = fminf(tg.y, 60.0f);
            }
            v2f ef = { fexp2(tf.x), fexp2(tf.y) };
            v2f eg = { fexp2(tg.x), fexp2(tg.y) };
            v2f num = ef - splat(1.0f);
            v2f den = (ef + splat(1.0f)) * (eg + splat(1.0f));
            v2f r   = { frcp(den.x), frcp(den.y) };
            v2f res = num * r;
            v[s] = res.x; v[s+1] = res.y;
        }
        if (len & 1) {
            const int s = len - 1;
            float a = v[s], b = v[s + 1];
            float tf = fmaf(a, ff0, fmaf(b, ff1, ffb));
            float tg = fmaf(a, gg0, fmaf(b, gg1, ggb));
            if (i == 0) { tf = fminf(tf, 60.0f); tg = fminf(tg, 60.0f); }
            float ef = fexp2(tf), eg = fexp2(tg);
            v[s] = (ef - 1.0f) * frcp((ef + 1.0f) * (eg + 1.0f));
        }
        if (edge) {
            #pragma unroll
            for (int s = 0; s < len; ++s)
                if (tbase + s >= TTOT) v[s] = 0.0f;
        }
    }

    // direct transposed store: out[t][n]; 64 lanes x 4B = contiguous 256B per
    // wave-store -> fully coalesced, no LDS, no barriers
    float* op = out + (size_t)tbase * NN + n0 + nl;
    #pragma unroll
    for (int s = 0; s < S; ++s)
        op[(size_t)s * NN] = v[s];
}

extern "C" void kernel_launch(void* const* d_in, const int* in_sizes, int n_in,
                              void* d_out, int out_size, void* d_ws, size_t ws_size,
                              hipStream_t stream) {
    const float* x  = (const float*)d_in[0];
    const float* sw = (const float*)d_in[1];
    const float* sb = (const float*)d_in[2];
    const float* fw = (const float*)d_in[3];
    const float* fb = (const float*)d_in[4];
    const float* gw = (const float*)d_in[5];
    const float* gb = (const float*)d_in[6];
    float* out = (float*)d_out;

    dim3 grid((NN / TN) * (TTOT / TB));   // 64 * 64 = 4096 blocks
    gdcn_kernel<<<grid, 256, 0, stream>>>(x, sw, sb, fw, fb, gw, gb, out);
}